// Round 1
// baseline (291.714 us; speedup 1.0000x reference)
//
#include <hip/hip_runtime.h>

// ActorGCN collapsed-linear implementation.
// Key identity: A(xW) = (Ax)W, and BN stats of h = yW+b reduce to the
// 20x20 covariance of y. Hidden [N,1024] never materialized.
//
// Workspace layout (floats):
//   deg   : [0,   N)
//   dinv  : [N,  2N)
//   y     : [2N, 2N + 20N)
//   stats : 256 floats (20 column sums + 210 upper-tri second moments)
//   params: 64 floats  (M[40], d[2], ybar[20])
// Total = 22N + 320 floats ~= 18.4 MB.

#define F 20
#define NSTAT 230  // 20 sums + 210 upper-triangle (incl diag) products

__global__ void k_deg_init(float* __restrict__ deg, int N) {
  int n = blockIdx.x * blockDim.x + threadIdx.x;
  if (n < N) deg[n] = 1.0f;  // self-loop contributes 1
}

__global__ void k_deg_acc(const int* __restrict__ dst, float* __restrict__ deg, int E) {
  int e = blockIdx.x * blockDim.x + threadIdx.x;
  if (e < E) atomicAdd(&deg[dst[e]], 1.0f);
}

// thread per (node, feature): y[n,f] = x[n,f]/deg[n]  (self-loop term, plain store)
// also emits dinv[n] = rsqrt(deg[n]) once per node.
__global__ void k_selfloop(const float* __restrict__ state,
                           const float* __restrict__ edge_attr,
                           const float* __restrict__ deg,
                           float* __restrict__ dinv,
                           float* __restrict__ y,
                           int N, int Ns) {
  int tid = blockIdx.x * blockDim.x + threadIdx.x;
  int total = N * F;
  if (tid >= total) return;
  int n = tid / F;
  int f = tid - n * F;
  float d = deg[n];
  int sb = Ns * F;
  float x = (tid < sb) ? state[tid] : edge_attr[tid - sb];
  y[tid] = x / d;                 // dinv[n]^2 * x = x/deg
  if (f == 0) dinv[n] = rsqrtf(d);
}

// thread per (edge, feature): y[dst,f] += dinv[src]*dinv[dst]*x[src,f]
__global__ void k_edge_scatter(const int* __restrict__ src,
                               const int* __restrict__ dst,
                               const float* __restrict__ dinv,
                               const float* __restrict__ state,
                               const float* __restrict__ edge_attr,
                               float* __restrict__ y,
                               int E, int Ns) {
  int tid = blockIdx.x * blockDim.x + threadIdx.x;
  if (tid >= E * F) return;
  int e = tid / F;
  int f = tid - e * F;
  int s = src[e];
  int d = dst[e];
  float norm = dinv[s] * dinv[d];
  int xi = s * F + f;
  int sb = Ns * F;
  float x = (xi < sb) ? state[xi] : edge_attr[xi - sb];
  atomicAdd(&y[d * F + f], norm * x);
}

// Column sums + upper-tri second moments of y, LDS-staged.
#define ROWS_CHUNK 256
#define CHUNKS 8  // 2048 rows per block
__global__ void k_stats(const float* __restrict__ y, float* __restrict__ stats, int N) {
  __shared__ float lds[ROWS_CHUNK * F];
  int c = threadIdx.x;
  int ci = 0, cj = 0;
  if (c >= F && c < NSTAT) {
    int k = c - F;
    int i = 0;
    while (k >= F - i) { k -= F - i; i++; }
    ci = i; cj = i + k;
  }
  float acc = 0.f;
  long rowbase = (long)blockIdx.x * (ROWS_CHUNK * CHUNKS);
  long totalElems = (long)N * F;
  for (int ch = 0; ch < CHUNKS; ++ch) {
    long e0 = (rowbase + (long)ch * ROWS_CHUNK) * F;
    for (int i = threadIdx.x; i < ROWS_CHUNK * F; i += blockDim.x) {
      long gi = e0 + i;
      lds[i] = (gi < totalElems) ? y[gi] : 0.f;
    }
    __syncthreads();
    if (c < F) {
      for (int r = 0; r < ROWS_CHUNK; ++r) acc += lds[r * F + c];
    } else if (c < NSTAT) {
      for (int r = 0; r < ROWS_CHUNK; ++r) acc += lds[r * F + ci] * lds[r * F + cj];
    }
    __syncthreads();
  }
  if (c < NSTAT) atomicAdd(&stats[c], acc);
}

// Single block: build ybar, C (20x20), per-channel scale, fold into M[20][2], d[2].
__global__ void k_finalize(const float* __restrict__ stats,
                           const float* __restrict__ W_gcn,
                           const float* __restrict__ gamma,
                           const float* __restrict__ beta,
                           const float* __restrict__ W_lin,
                           const float* __restrict__ b_lin,
                           float* __restrict__ params,
                           int N, int H) {
  __shared__ float C[F][F];
  __shared__ float ybar_s[F];
  __shared__ float sg[1024];
  int t = threadIdx.x;
  float invN = 1.0f / (float)N;
  if (t < F) ybar_s[t] = stats[t] * invN;
  __syncthreads();
  if (t >= F && t < NSTAT) {
    int k = t - F;
    int i = 0;
    while (k >= F - i) { k -= F - i; i++; }
    int j = i + k;
    float cv = stats[t] * invN - ybar_s[i] * ybar_s[j];
    C[i][j] = cv;
    C[j][i] = cv;
  }
  __syncthreads();
  for (int h = t; h < H; h += blockDim.x) {
    float w[F];
    #pragma unroll
    for (int f = 0; f < F; ++f) w[f] = W_gcn[f * H + h];
    float var = 0.f;
    #pragma unroll
    for (int i = 0; i < F; ++i) {
      float ti = 0.f;
      #pragma unroll
      for (int j = 0; j < F; ++j) ti += C[i][j] * w[j];
      var += w[i] * ti;
    }
    sg[h] = gamma[h] * rsqrtf(var + 1e-5f);
  }
  __syncthreads();
  if (t < 2 * F) {                 // M[f][o], index t = f*2+o
    int f = t >> 1, o = t & 1;
    float acc = 0.f;
    for (int h = 0; h < H; ++h) acc += W_gcn[f * H + h] * sg[h] * W_lin[h * 2 + o];
    params[t] = acc;
  } else if (t < 2 * F + 2) {      // d[o]
    int o = t - 2 * F;
    float acc = b_lin[o];
    for (int h = 0; h < H; ++h) acc += beta[h] * W_lin[h * 2 + o];
    params[40 + o] = acc;
  } else if (t < 2 * F + 2 + F) {  // ybar
    params[t] = ybar_s[t - 42];
  }
}

// thread per node: logits = (y[n]-ybar) @ M + d; relu; 2-way softmax.
__global__ void k_out(const float* __restrict__ y,
                      const float* __restrict__ params,
                      float* __restrict__ out, int N) {
  __shared__ float P[64];
  if (threadIdx.x < 62) P[threadIdx.x] = params[threadIdx.x];
  __syncthreads();
  int n = blockIdx.x * blockDim.x + threadIdx.x;
  if (n >= N) return;
  const float4* yr4 = reinterpret_cast<const float4*>(y + (size_t)n * F);
  float v[F];
  #pragma unroll
  for (int k = 0; k < 5; ++k) {
    float4 q = yr4[k];
    v[4 * k + 0] = q.x; v[4 * k + 1] = q.y;
    v[4 * k + 2] = q.z; v[4 * k + 3] = q.w;
  }
  float l0 = P[40], l1 = P[41];
  #pragma unroll
  for (int f = 0; f < F; ++f) {
    float dv = v[f] - P[42 + f];
    l0 += dv * P[f * 2 + 0];
    l1 += dv * P[f * 2 + 1];
  }
  l0 = fmaxf(l0, 0.f);
  l1 = fmaxf(l1, 0.f);
  float m = fmaxf(l0, l1);
  float e0 = __expf(l0 - m), e1 = __expf(l1 - m);
  float inv = 1.0f / (e0 + e1);
  float2 o2; o2.x = e0 * inv; o2.y = e1 * inv;
  reinterpret_cast<float2*>(out)[n] = o2;
}

extern "C" void kernel_launch(void* const* d_in, const int* in_sizes, int n_in,
                              void* d_out, int out_size, void* d_ws, size_t ws_size,
                              hipStream_t stream) {
  const float* state     = (const float*)d_in[0];
  const float* edge_attr = (const float*)d_in[1];
  const int*   eidx      = (const int*)d_in[2];
  const float* W_gcn     = (const float*)d_in[3];
  // d_in[4] = b_gcn: cancels inside batchnorm, unused.
  const float* gamma     = (const float*)d_in[5];
  const float* beta      = (const float*)d_in[6];
  const float* W_lin     = (const float*)d_in[7];
  const float* b_lin     = (const float*)d_in[8];
  float* out = (float*)d_out;

  int Ns = in_sizes[0] / F;
  int E  = in_sizes[2] / 2;
  int N  = Ns + in_sizes[1] / F;
  int H  = in_sizes[4];

  const int* src = eidx;
  const int* dst = eidx + E;

  float* ws     = (float*)d_ws;
  float* deg    = ws;
  float* dinv   = ws + N;
  float* y      = ws + 2 * (size_t)N;
  float* stats  = y + (size_t)N * F;
  float* params = stats + 256;

  hipMemsetAsync(stats, 0, 256 * sizeof(float), stream);

  const int B = 256;
  k_deg_init<<<(N + B - 1) / B, B, 0, stream>>>(deg, N);
  k_deg_acc<<<(E + B - 1) / B, B, 0, stream>>>(dst, deg, E);
  k_selfloop<<<(N * F + B - 1) / B, B, 0, stream>>>(state, edge_attr, deg, dinv, y, N, Ns);
  k_edge_scatter<<<(E * F + B - 1) / B, B, 0, stream>>>(src, dst, dinv, state, edge_attr, y, E, Ns);
  k_stats<<<(N + ROWS_CHUNK * CHUNKS - 1) / (ROWS_CHUNK * CHUNKS), B, 0, stream>>>(y, stats, N);
  k_finalize<<<1, B, 0, stream>>>(stats, W_gcn, gamma, beta, W_lin, b_lin, params, N, H);
  k_out<<<(N + B - 1) / B, B, 0, stream>>>(y, params, out, N);
}

// Round 2
// 240.425 us; speedup vs baseline: 1.2133x; 1.2133x over previous
//
#include <hip/hip_runtime.h>

// ActorGCN collapsed-linear implementation.
// Key identity: A(xW) = (Ax)W, and BN stats of h = yW+b reduce to the
// 20x20 covariance of y. Hidden [N,1024] never materialized.
//
// Workspace layout (floats):
//   deg   : [0,   N)
//   dinv  : [N,  2N)
//   y     : [2N, 2N + 20N)
//   stats : 256 floats (20 column sums + 210 upper-tri second moments)
//   params: 64 floats  (M[40], d[2], ybar[20])
// Total = 22N + 320 floats ~= 18.4 MB.

#define F 20
#define NSTAT 230  // 20 sums + 210 upper-triangle (incl diag) products

__global__ void k_deg_init(float* __restrict__ deg, int N) {
  int n = blockIdx.x * blockDim.x + threadIdx.x;
  if (n < N) deg[n] = 1.0f;  // self-loop contributes 1
}

__global__ void k_deg_acc(const int* __restrict__ dst, float* __restrict__ deg, int E) {
  int e = blockIdx.x * blockDim.x + threadIdx.x;
  if (e < E) atomicAdd(&deg[dst[e]], 1.0f);
}

// thread per (node, feature): y[n,f] = x[n,f]/deg[n]  (self-loop term, plain store)
// also emits dinv[n] = rsqrt(deg[n]) once per node.
__global__ void k_selfloop(const float* __restrict__ state,
                           const float* __restrict__ edge_attr,
                           const float* __restrict__ deg,
                           float* __restrict__ dinv,
                           float* __restrict__ y,
                           int N, int Ns) {
  int tid = blockIdx.x * blockDim.x + threadIdx.x;
  int total = N * F;
  if (tid >= total) return;
  int n = tid / F;
  int f = tid - n * F;
  float d = deg[n];
  int sb = Ns * F;
  float x = (tid < sb) ? state[tid] : edge_attr[tid - sb];
  y[tid] = x / d;                 // dinv[n]^2 * x = x/deg
  if (f == 0) dinv[n] = rsqrtf(d);
}

// thread per (edge, feature): y[dst,f] += dinv[src]*dinv[dst]*x[src,f]
__global__ void k_edge_scatter(const int* __restrict__ src,
                               const int* __restrict__ dst,
                               const float* __restrict__ dinv,
                               const float* __restrict__ state,
                               const float* __restrict__ edge_attr,
                               float* __restrict__ y,
                               int E, int Ns) {
  int tid = blockIdx.x * blockDim.x + threadIdx.x;
  if (tid >= E * F) return;
  int e = tid / F;
  int f = tid - e * F;
  int s = src[e];
  int d = dst[e];
  float norm = dinv[s] * dinv[d];
  int xi = s * F + f;
  int sb = Ns * F;
  float x = (xi < sb) ? state[xi] : edge_attr[xi - sb];
  atomicAdd(&y[d * F + f], norm * x);
}

// Column sums + upper-tri second moments of y, LDS-staged.
#define ROWS_CHUNK 256
#define CHUNKS 8  // 2048 rows per block
__global__ void k_stats(const float* __restrict__ y, float* __restrict__ stats, int N) {
  __shared__ float lds[ROWS_CHUNK * F];
  int c = threadIdx.x;
  int ci = 0, cj = 0;
  if (c >= F && c < NSTAT) {
    int k = c - F;
    int i = 0;
    while (k >= F - i) { k -= F - i; i++; }
    ci = i; cj = i + k;
  }
  float acc = 0.f;
  long rowbase = (long)blockIdx.x * (ROWS_CHUNK * CHUNKS);
  long totalElems = (long)N * F;
  for (int ch = 0; ch < CHUNKS; ++ch) {
    long e0 = (rowbase + (long)ch * ROWS_CHUNK) * F;
    for (int i = threadIdx.x; i < ROWS_CHUNK * F; i += blockDim.x) {
      long gi = e0 + i;
      lds[i] = (gi < totalElems) ? y[gi] : 0.f;
    }
    __syncthreads();
    if (c < F) {
      for (int r = 0; r < ROWS_CHUNK; ++r) acc += lds[r * F + c];
    } else if (c < NSTAT) {
      for (int r = 0; r < ROWS_CHUNK; ++r) acc += lds[r * F + ci] * lds[r * F + cj];
    }
    __syncthreads();
  }
  if (c < NSTAT) atomicAdd(&stats[c], acc);
}

// Single block, 1024 threads (thread == hidden channel h).
// Phase 1: C (20x20 covariance) from stats.
// Phase 2: each thread h computes sg[h] = gamma[h]*rsqrt(w_h^T C w_h + eps)
//          with w_h kept in registers (W_gcn loads coalesced across h).
// Phase 3: per-thread partials of M[20][2] and d[2], wave shfl_xor butterfly
//          reduce, then 16-wave LDS reduce. Fully parallel — replaces the
//          40-thread x 1024-serial-global-load loop that cost 165 us.
__global__ __launch_bounds__(1024) void k_finalize(
    const float* __restrict__ stats,
    const float* __restrict__ W_gcn,
    const float* __restrict__ gamma,
    const float* __restrict__ beta,
    const float* __restrict__ W_lin,
    const float* __restrict__ b_lin,
    float* __restrict__ params,
    int N, int H) {
  __shared__ float C[F][F];
  __shared__ float ybar_s[F];
  __shared__ float part[16][44];  // [wave][42 outputs], padded
  int t = threadIdx.x;
  int lane = t & 63;
  int wv = t >> 6;
  float invN = 1.0f / (float)N;
  if (t < F) ybar_s[t] = stats[t] * invN;
  __syncthreads();
  if (t >= F && t < NSTAT) {
    int k = t - F;
    int i = 0;
    while (k >= F - i) { k -= F - i; i++; }
    int j = i + k;
    float cv = stats[t] * invN - ybar_s[i] * ybar_s[j];
    C[i][j] = cv;
    C[j][i] = cv;
  }
  __syncthreads();

  float m0[F], m1[F];
  #pragma unroll
  for (int f = 0; f < F; ++f) { m0[f] = 0.f; m1[f] = 0.f; }
  float d0 = 0.f, d1 = 0.f;

  for (int h = t; h < H; h += blockDim.x) {
    float w[F];
    #pragma unroll
    for (int f = 0; f < F; ++f) w[f] = W_gcn[f * H + h];  // coalesced over h
    float var = 0.f;
    #pragma unroll
    for (int i = 0; i < F; ++i) {
      float ti = 0.f;
      #pragma unroll
      for (int j = 0; j < F; ++j) ti += C[i][j] * w[j];  // LDS broadcast
      var += w[i] * ti;
    }
    float sg = gamma[h] * rsqrtf(var + 1e-5f);
    float wl0 = W_lin[h * 2 + 0], wl1 = W_lin[h * 2 + 1];
    float s0 = sg * wl0, s1 = sg * wl1;
    #pragma unroll
    for (int f = 0; f < F; ++f) { m0[f] += w[f] * s0; m1[f] += w[f] * s1; }
    float bt = beta[h];
    d0 += bt * wl0;
    d1 += bt * wl1;
  }

  // butterfly reduce each partial across the 64-lane wave
  #pragma unroll
  for (int f = 0; f < F; ++f) {
    float v0 = m0[f], v1 = m1[f];
    for (int off = 32; off; off >>= 1) {
      v0 += __shfl_xor(v0, off);
      v1 += __shfl_xor(v1, off);
    }
    if (lane == 0) { part[wv][2 * f] = v0; part[wv][2 * f + 1] = v1; }
  }
  for (int off = 32; off; off >>= 1) {
    d0 += __shfl_xor(d0, off);
    d1 += __shfl_xor(d1, off);
  }
  if (lane == 0) { part[wv][40] = d0; part[wv][41] = d1; }
  __syncthreads();

  int nw = blockDim.x >> 6;
  if (t < 42) {
    float acc = 0.f;
    for (int w2 = 0; w2 < nw; ++w2) acc += part[w2][t];
    if (t >= 40) acc += b_lin[t - 40];
    params[t] = acc;
  } else if (t >= 42 && t < 62) {
    params[t] = ybar_s[t - 42];
  }
}

// thread per node: logits = (y[n]-ybar) @ M + d; relu; 2-way softmax.
__global__ void k_out(const float* __restrict__ y,
                      const float* __restrict__ params,
                      float* __restrict__ out, int N) {
  __shared__ float P[64];
  if (threadIdx.x < 62) P[threadIdx.x] = params[threadIdx.x];
  __syncthreads();
  int n = blockIdx.x * blockDim.x + threadIdx.x;
  if (n >= N) return;
  const float4* yr4 = reinterpret_cast<const float4*>(y + (size_t)n * F);
  float v[F];
  #pragma unroll
  for (int k = 0; k < 5; ++k) {
    float4 q = yr4[k];
    v[4 * k + 0] = q.x; v[4 * k + 1] = q.y;
    v[4 * k + 2] = q.z; v[4 * k + 3] = q.w;
  }
  float l0 = P[40], l1 = P[41];
  #pragma unroll
  for (int f = 0; f < F; ++f) {
    float dv = v[f] - P[42 + f];
    l0 += dv * P[f * 2 + 0];
    l1 += dv * P[f * 2 + 1];
  }
  l0 = fmaxf(l0, 0.f);
  l1 = fmaxf(l1, 0.f);
  float m = fmaxf(l0, l1);
  float e0 = __expf(l0 - m), e1 = __expf(l1 - m);
  float inv = 1.0f / (e0 + e1);
  float2 o2; o2.x = e0 * inv; o2.y = e1 * inv;
  reinterpret_cast<float2*>(out)[n] = o2;
}

extern "C" void kernel_launch(void* const* d_in, const int* in_sizes, int n_in,
                              void* d_out, int out_size, void* d_ws, size_t ws_size,
                              hipStream_t stream) {
  const float* state     = (const float*)d_in[0];
  const float* edge_attr = (const float*)d_in[1];
  const int*   eidx      = (const int*)d_in[2];
  const float* W_gcn     = (const float*)d_in[3];
  // d_in[4] = b_gcn: cancels inside batchnorm, unused.
  const float* gamma     = (const float*)d_in[5];
  const float* beta      = (const float*)d_in[6];
  const float* W_lin     = (const float*)d_in[7];
  const float* b_lin     = (const float*)d_in[8];
  float* out = (float*)d_out;

  int Ns = in_sizes[0] / F;
  int E  = in_sizes[2] / 2;
  int N  = Ns + in_sizes[1] / F;
  int H  = in_sizes[4];

  const int* src = eidx;
  const int* dst = eidx + E;

  float* ws     = (float*)d_ws;
  float* deg    = ws;
  float* dinv   = ws + N;
  float* y      = ws + 2 * (size_t)N;
  float* stats  = y + (size_t)N * F;
  float* params = stats + 256;

  hipMemsetAsync(stats, 0, 256 * sizeof(float), stream);

  const int B = 256;
  k_deg_init<<<(N + B - 1) / B, B, 0, stream>>>(deg, N);
  k_deg_acc<<<(E + B - 1) / B, B, 0, stream>>>(dst, deg, E);
  k_selfloop<<<(N * F + B - 1) / B, B, 0, stream>>>(state, edge_attr, deg, dinv, y, N, Ns);
  k_edge_scatter<<<(E * F + B - 1) / B, B, 0, stream>>>(src, dst, dinv, state, edge_attr, y, E, Ns);
  k_stats<<<(N + ROWS_CHUNK * CHUNKS - 1) / (ROWS_CHUNK * CHUNKS), B, 0, stream>>>(y, stats, N);
  k_finalize<<<1, 1024, 0, stream>>>(stats, W_gcn, gamma, beta, W_lin, b_lin, params, N, H);
  k_out<<<(N + B - 1) / B, B, 0, stream>>>(y, params, out, N);
}

// Round 3
// 235.365 us; speedup vs baseline: 1.2394x; 1.0215x over previous
//
#include <hip/hip_runtime.h>

// ActorGCN collapsed-linear implementation.
// Key identity: A(xW) = (Ax)W, and BN stats of h = yW+b reduce to the
// 20x20 covariance of y. Hidden [N,1024] never materialized.
//
// Workspace layout (floats):
//   deg   : [0,   N)
//   dinv  : [N,  2N)
//   y     : [2N, 2N + 20N)
//   stats : 256 floats (20 column sums + 210 upper-tri second moments)
//   params: 64 floats  (M[40], d[2], ybar[20])
// Total = 22N + 320 floats ~= 18.4 MB.

#define F 20
#define NSTAT 230  // 20 sums + 210 upper-triangle (incl diag) products

__global__ void k_deg_init(float* __restrict__ deg, int N) {
  int n = blockIdx.x * blockDim.x + threadIdx.x;
  if (n < N) deg[n] = 1.0f;  // self-loop contributes 1
}

__global__ void k_deg_acc(const int* __restrict__ dst, float* __restrict__ deg, int E) {
  int e = blockIdx.x * blockDim.x + threadIdx.x;
  if (e < E) atomicAdd(&deg[dst[e]], 1.0f);
}

// thread per (node, feature): y[n,f] = x[n,f]/deg[n]  (self-loop term, plain store)
// also emits dinv[n] = rsqrt(deg[n]) once per node.
__global__ void k_selfloop(const float* __restrict__ state,
                           const float* __restrict__ edge_attr,
                           const float* __restrict__ deg,
                           float* __restrict__ dinv,
                           float* __restrict__ y,
                           int N, int Ns) {
  int tid = blockIdx.x * blockDim.x + threadIdx.x;
  int total = N * F;
  if (tid >= total) return;
  int n = tid / F;
  int f = tid - n * F;
  float d = deg[n];
  int sb = Ns * F;
  float x = (tid < sb) ? state[tid] : edge_attr[tid - sb];
  y[tid] = x / d;                 // dinv[n]^2 * x = x/deg
  if (f == 0) dinv[n] = rsqrtf(d);
}

// thread per (edge, feature): y[dst,f] += dinv[src]*dinv[dst]*x[src,f]
__global__ void k_edge_scatter(const int* __restrict__ src,
                               const int* __restrict__ dst,
                               const float* __restrict__ dinv,
                               const float* __restrict__ state,
                               const float* __restrict__ edge_attr,
                               float* __restrict__ y,
                               int E, int Ns) {
  int tid = blockIdx.x * blockDim.x + threadIdx.x;
  if (tid >= E * F) return;
  int e = tid / F;
  int f = tid - e * F;
  int s = src[e];
  int d = dst[e];
  float norm = dinv[s] * dinv[d];
  int xi = s * F + f;
  int sb = Ns * F;
  float x = (xi < sb) ? state[xi] : edge_attr[xi - sb];
  atomicAdd(&y[d * F + f], norm * x);
}

// Column sums + upper-tri second moments of y, LDS-staged.
#define ROWS_CHUNK 256
#define CHUNKS 8  // 2048 rows per block
__global__ void k_stats(const float* __restrict__ y, float* __restrict__ stats, int N) {
  __shared__ float lds[ROWS_CHUNK * F];
  int c = threadIdx.x;
  int ci = 0, cj = 0;
  if (c >= F && c < NSTAT) {
    int k = c - F;
    int i = 0;
    while (k >= F - i) { k -= F - i; i++; }
    ci = i; cj = i + k;
  }
  float acc = 0.f;
  long rowbase = (long)blockIdx.x * (ROWS_CHUNK * CHUNKS);
  long totalElems = (long)N * F;
  for (int ch = 0; ch < CHUNKS; ++ch) {
    long e0 = (rowbase + (long)ch * ROWS_CHUNK) * F;
    for (int i = threadIdx.x; i < ROWS_CHUNK * F; i += blockDim.x) {
      long gi = e0 + i;
      lds[i] = (gi < totalElems) ? y[gi] : 0.f;
    }
    __syncthreads();
    if (c < F) {
      for (int r = 0; r < ROWS_CHUNK; ++r) acc += lds[r * F + c];
    } else if (c < NSTAT) {
      for (int r = 0; r < ROWS_CHUNK; ++r) acc += lds[r * F + ci] * lds[r * F + cj];
    }
    __syncthreads();
  }
  if (c < NSTAT) atomicAdd(&stats[c], acc);
}

// Single block, 1024 threads (thread == hidden channel h).
// Register-light: per f, the m-contribution w[f]*s0/s1 is butterfly-reduced
// IMMEDIATELY (6 shuffles) and accumulated into LDS by lane 0 — no m0[20]/
// m1[20] accumulator arrays. Live state = w[20] + ~10 scalars, so no scratch
// spill at the 64-VGPR/16-wave cap (round-2 version spilled: WRITE_SIZE 1.5 MB,
// VALUBusy 0.02%, 118 us).
__global__ __launch_bounds__(1024) void k_finalize(
    const float* __restrict__ stats,
    const float* __restrict__ W_gcn,
    const float* __restrict__ gamma,
    const float* __restrict__ beta,
    const float* __restrict__ W_lin,
    const float* __restrict__ b_lin,
    float* __restrict__ params,
    int N, int H) {
  __shared__ float C[F][F];
  __shared__ float ybar_s[F];
  __shared__ float part[16][44];  // [wave][42 outputs], padded
  int t = threadIdx.x;
  int lane = t & 63;
  int wv = t >> 6;
  float invN = 1.0f / (float)N;
  if (t < 16 * 44) ((float*)part)[t] = 0.f;
  if (t < F) ybar_s[t] = stats[t] * invN;
  __syncthreads();
  if (t >= F && t < NSTAT) {
    int k = t - F;
    int i = 0;
    while (k >= F - i) { k -= F - i; i++; }
    int j = i + k;
    float cv = stats[t] * invN - ybar_s[i] * ybar_s[j];
    C[i][j] = cv;
    C[j][i] = cv;
  }
  __syncthreads();

  for (int h0 = 0; h0 < H; h0 += blockDim.x) {
    int h = h0 + t;
    bool act = (h < H);
    int hc = act ? h : (H - 1);  // clamp address, zero the value
    float w[F];
    #pragma unroll
    for (int f = 0; f < F; ++f) {
      float wv_ = W_gcn[f * H + hc];  // coalesced over h
      w[f] = act ? wv_ : 0.f;
    }
    float var = 0.f;
    #pragma unroll
    for (int i = 0; i < F; ++i) {
      float ti = 0.f;
      #pragma unroll
      for (int j = 0; j < F; ++j) ti += C[i][j] * w[j];  // uniform LDS broadcast
      var += w[i] * ti;
    }
    float sg = act ? (gamma[hc] * rsqrtf(var + 1e-5f)) : 0.f;
    float wl0 = W_lin[hc * 2 + 0], wl1 = W_lin[hc * 2 + 1];
    float s0 = sg * wl0, s1 = sg * wl1;

    // immediate per-f butterfly: no persistent accumulator arrays
    #pragma unroll
    for (int f = 0; f < F; ++f) {
      float v0 = w[f] * s0, v1 = w[f] * s1;
      #pragma unroll
      for (int off = 32; off; off >>= 1) {
        v0 += __shfl_xor(v0, off);
        v1 += __shfl_xor(v1, off);
      }
      if (lane == 0) { part[wv][2 * f] += v0; part[wv][2 * f + 1] += v1; }
    }
    float bt = act ? beta[hc] : 0.f;
    float d0 = bt * wl0, d1 = bt * wl1;
    #pragma unroll
    for (int off = 32; off; off >>= 1) {
      d0 += __shfl_xor(d0, off);
      d1 += __shfl_xor(d1, off);
    }
    if (lane == 0) { part[wv][40] += d0; part[wv][41] += d1; }
  }
  __syncthreads();

  int nw = blockDim.x >> 6;
  if (t < 42) {
    float acc = 0.f;
    for (int w2 = 0; w2 < nw; ++w2) acc += part[w2][t];
    if (t >= 40) acc += b_lin[t - 40];
    params[t] = acc;
  } else if (t >= 42 && t < 62) {
    params[t] = ybar_s[t - 42];
  }
}

// thread per node: logits = (y[n]-ybar) @ M + d; relu; 2-way softmax.
__global__ void k_out(const float* __restrict__ y,
                      const float* __restrict__ params,
                      float* __restrict__ out, int N) {
  __shared__ float P[64];
  if (threadIdx.x < 62) P[threadIdx.x] = params[threadIdx.x];
  __syncthreads();
  int n = blockIdx.x * blockDim.x + threadIdx.x;
  if (n >= N) return;
  const float4* yr4 = reinterpret_cast<const float4*>(y + (size_t)n * F);
  float v[F];
  #pragma unroll
  for (int k = 0; k < 5; ++k) {
    float4 q = yr4[k];
    v[4 * k + 0] = q.x; v[4 * k + 1] = q.y;
    v[4 * k + 2] = q.z; v[4 * k + 3] = q.w;
  }
  float l0 = P[40], l1 = P[41];
  #pragma unroll
  for (int f = 0; f < F; ++f) {
    float dv = v[f] - P[42 + f];
    l0 += dv * P[f * 2 + 0];
    l1 += dv * P[f * 2 + 1];
  }
  l0 = fmaxf(l0, 0.f);
  l1 = fmaxf(l1, 0.f);
  float m = fmaxf(l0, l1);
  float e0 = __expf(l0 - m), e1 = __expf(l1 - m);
  float inv = 1.0f / (e0 + e1);
  float2 o2; o2.x = e0 * inv; o2.y = e1 * inv;
  reinterpret_cast<float2*>(out)[n] = o2;
}

extern "C" void kernel_launch(void* const* d_in, const int* in_sizes, int n_in,
                              void* d_out, int out_size, void* d_ws, size_t ws_size,
                              hipStream_t stream) {
  const float* state     = (const float*)d_in[0];
  const float* edge_attr = (const float*)d_in[1];
  const int*   eidx      = (const int*)d_in[2];
  const float* W_gcn     = (const float*)d_in[3];
  // d_in[4] = b_gcn: cancels inside batchnorm, unused.
  const float* gamma     = (const float*)d_in[5];
  const float* beta      = (const float*)d_in[6];
  const float* W_lin     = (const float*)d_in[7];
  const float* b_lin     = (const float*)d_in[8];
  float* out = (float*)d_out;

  int Ns = in_sizes[0] / F;
  int E  = in_sizes[2] / 2;
  int N  = Ns + in_sizes[1] / F;
  int H  = in_sizes[4];

  const int* src = eidx;
  const int* dst = eidx + E;

  float* ws     = (float*)d_ws;
  float* deg    = ws;
  float* dinv   = ws + N;
  float* y      = ws + 2 * (size_t)N;
  float* stats  = y + (size_t)N * F;
  float* params = stats + 256;

  hipMemsetAsync(stats, 0, 256 * sizeof(float), stream);

  const int B = 256;
  k_deg_init<<<(N + B - 1) / B, B, 0, stream>>>(deg, N);
  k_deg_acc<<<(E + B - 1) / B, B, 0, stream>>>(dst, deg, E);
  k_selfloop<<<(N * F + B - 1) / B, B, 0, stream>>>(state, edge_attr, deg, dinv, y, N, Ns);
  k_edge_scatter<<<(E * F + B - 1) / B, B, 0, stream>>>(src, dst, dinv, state, edge_attr, y, E, Ns);
  k_stats<<<(N + ROWS_CHUNK * CHUNKS - 1) / (ROWS_CHUNK * CHUNKS), B, 0, stream>>>(y, stats, N);
  k_finalize<<<1, 1024, 0, stream>>>(stats, W_gcn, gamma, beta, W_lin, b_lin, params, N, H);
  k_out<<<(N + B - 1) / B, B, 0, stream>>>(y, params, out, N);
}

// Round 4
// 152.087 us; speedup vs baseline: 1.9181x; 1.5476x over previous
//
#include <hip/hip_runtime.h>

// ActorGCN collapsed-linear implementation.
// Key identity: A(xW) = (Ax)W, and BN stats of h = yW+b reduce to the
// 20x20 covariance of y. Hidden [N,1024] never materialized.
//
// Workspace layout (floats):
//   deg   : [0,   N)
//   dinv  : [N,  2N)
//   y     : [2N, 2N + 20N)
//   stats : 256 floats (20 column sums + 210 upper-tri second moments)
//   params: 64 floats  (M[40], d[2], ybar[20])
// Total = 22N + 320 floats ~= 18.4 MB.

#define F 20
#define NSTAT 230  // 20 sums + 210 upper-triangle (incl diag) products

__global__ void k_deg_init(float* __restrict__ deg, int N) {
  int n = blockIdx.x * blockDim.x + threadIdx.x;
  if (n < N) deg[n] = 1.0f;  // self-loop contributes 1
}

__global__ void k_deg_acc(const int* __restrict__ dst, float* __restrict__ deg, int E) {
  int e = blockIdx.x * blockDim.x + threadIdx.x;
  if (e < E) atomicAdd(&deg[dst[e]], 1.0f);
}

// thread per (node, feature): y[n,f] = x[n,f]/deg[n]  (self-loop term, plain store)
// also emits dinv[n] = rsqrt(deg[n]) once per node.
__global__ void k_selfloop(const float* __restrict__ state,
                           const float* __restrict__ edge_attr,
                           const float* __restrict__ deg,
                           float* __restrict__ dinv,
                           float* __restrict__ y,
                           int N, int Ns) {
  int tid = blockIdx.x * blockDim.x + threadIdx.x;
  int total = N * F;
  if (tid >= total) return;
  int n = tid / F;
  int f = tid - n * F;
  float d = deg[n];
  int sb = Ns * F;
  float x = (tid < sb) ? state[tid] : edge_attr[tid - sb];
  y[tid] = x / d;                 // dinv[n]^2 * x = x/deg
  if (f == 0) dinv[n] = rsqrtf(d);
}

// thread per (edge, feature): y[dst,f] += dinv[src]*dinv[dst]*x[src,f]
__global__ void k_edge_scatter(const int* __restrict__ src,
                               const int* __restrict__ dst,
                               const float* __restrict__ dinv,
                               const float* __restrict__ state,
                               const float* __restrict__ edge_attr,
                               float* __restrict__ y,
                               int E, int Ns) {
  int tid = blockIdx.x * blockDim.x + threadIdx.x;
  if (tid >= E * F) return;
  int e = tid / F;
  int f = tid - e * F;
  int s = src[e];
  int d = dst[e];
  float norm = dinv[s] * dinv[d];
  int xi = s * F + f;
  int sb = Ns * F;
  float x = (xi < sb) ? state[xi] : edge_attr[xi - sb];
  atomicAdd(&y[d * F + f], norm * x);
}

// Column sums + upper-tri second moments of y, LDS-staged.
#define ROWS_CHUNK 256
#define CHUNKS 8  // 2048 rows per block
__global__ void k_stats(const float* __restrict__ y, float* __restrict__ stats, int N) {
  __shared__ float lds[ROWS_CHUNK * F];
  int c = threadIdx.x;
  int ci = 0, cj = 0;
  if (c >= F && c < NSTAT) {
    int k = c - F;
    int i = 0;
    while (k >= F - i) { k -= F - i; i++; }
    ci = i; cj = i + k;
  }
  float acc = 0.f;
  long rowbase = (long)blockIdx.x * (ROWS_CHUNK * CHUNKS);
  long totalElems = (long)N * F;
  for (int ch = 0; ch < CHUNKS; ++ch) {
    long e0 = (rowbase + (long)ch * ROWS_CHUNK) * F;
    for (int i = threadIdx.x; i < ROWS_CHUNK * F; i += blockDim.x) {
      long gi = e0 + i;
      lds[i] = (gi < totalElems) ? y[gi] : 0.f;
    }
    __syncthreads();
    if (c < F) {
      for (int r = 0; r < ROWS_CHUNK; ++r) acc += lds[r * F + c];
    } else if (c < NSTAT) {
      for (int r = 0; r < ROWS_CHUNK; ++r) acc += lds[r * F + ci] * lds[r * F + cj];
    }
    __syncthreads();
  }
  if (c < NSTAT) atomicAdd(&stats[c], acc);
}

// Single block, 256 threads, launch_bounds(256,1): 4 waves -> up to 512
// VGPR/thread, so w[4][20] + m0[20] + m1[20] live comfortably in registers.
// (Rounds 2-3 at 1024 threads were capped at 64 VGPR -> scratch spill ->
// WRITE_SIZE 1.4-1.5 MB, VALUBusy 0.02%, ~110-118 us.)
// Quadform uses 210 upper-tri covariance coeffs (off-diag premultiplied by 2)
// built once in LDS; each coeff is a uniform broadcast ds_read reused for the
// thread's 4 channels. Butterfly reduce runs ONCE at the end.
__global__ __launch_bounds__(256, 1) void k_finalize(
    const float* __restrict__ stats,
    const float* __restrict__ W_gcn,
    const float* __restrict__ gamma,
    const float* __restrict__ beta,
    const float* __restrict__ W_lin,
    const float* __restrict__ b_lin,
    float* __restrict__ params,
    int N, int H) {
  __shared__ float Cu_s[210];
  __shared__ float ybar_s[F];
  __shared__ float part[4][44];
  int t = threadIdx.x;
  int lane = t & 63;
  int wv = t >> 6;
  float invN = 1.0f / (float)N;
  if (t < F) ybar_s[t] = stats[t] * invN;
  __syncthreads();
  if (t < 210) {
    int k = t;
    int i = 0;
    while (k >= F - i) { k -= F - i; i++; }
    int j = i + k;
    float cv = stats[F + t] * invN - ybar_s[i] * ybar_s[j];
    Cu_s[t] = (i == j) ? cv : 2.0f * cv;  // fold symmetry factor
  }
  __syncthreads();

  float m0[F], m1[F];
  #pragma unroll
  for (int f = 0; f < F; ++f) { m0[f] = 0.f; m1[f] = 0.f; }
  float d0 = 0.f, d1 = 0.f;

  for (int hb = 0; hb < H; hb += 4 * 256) {
    float w[4][F];
    float var[4];
    int hh[4];
    bool act[4];
    #pragma unroll
    for (int c = 0; c < 4; ++c) {
      int h = hb + c * 256 + t;
      act[c] = (h < H);
      hh[c] = act[c] ? h : 0;
      var[c] = 0.f;
      #pragma unroll
      for (int f = 0; f < F; ++f) {
        float x = W_gcn[f * H + hh[c]];  // coalesced over t
        w[c][f] = act[c] ? x : 0.f;
      }
    }
    int p = 0;
    #pragma unroll
    for (int i = 0; i < F; ++i) {
      #pragma unroll
      for (int j = i; j < F; ++j) {
        float cu = Cu_s[p];  // uniform broadcast, reused 4x
        ++p;
        #pragma unroll
        for (int c = 0; c < 4; ++c) var[c] += cu * (w[c][i] * w[c][j]);
      }
    }
    #pragma unroll
    for (int c = 0; c < 4; ++c) {
      float sg = act[c] ? (gamma[hh[c]] * rsqrtf(var[c] + 1e-5f)) : 0.f;
      float wl0 = W_lin[hh[c] * 2 + 0], wl1 = W_lin[hh[c] * 2 + 1];
      float s0 = sg * wl0, s1 = sg * wl1;
      #pragma unroll
      for (int f = 0; f < F; ++f) { m0[f] += w[c][f] * s0; m1[f] += w[c][f] * s1; }
      float bt = act[c] ? beta[hh[c]] : 0.f;
      d0 += bt * wl0;
      d1 += bt * wl1;
    }
  }

  // one butterfly reduce at the end
  #pragma unroll
  for (int f = 0; f < F; ++f) {
    float v0 = m0[f], v1 = m1[f];
    #pragma unroll
    for (int off = 32; off; off >>= 1) {
      v0 += __shfl_xor(v0, off);
      v1 += __shfl_xor(v1, off);
    }
    if (lane == 0) { part[wv][2 * f] = v0; part[wv][2 * f + 1] = v1; }
  }
  #pragma unroll
  for (int off = 32; off; off >>= 1) {
    d0 += __shfl_xor(d0, off);
    d1 += __shfl_xor(d1, off);
  }
  if (lane == 0) { part[wv][40] = d0; part[wv][41] = d1; }
  __syncthreads();

  if (t < 42) {
    float acc = 0.f;
    for (int w2 = 0; w2 < 4; ++w2) acc += part[w2][t];
    if (t >= 40) acc += b_lin[t - 40];
    params[t] = acc;
  } else if (t < 62) {
    params[t] = ybar_s[t - 42];
  }
}

// thread per node: logits = (y[n]-ybar) @ M + d; relu; 2-way softmax.
__global__ void k_out(const float* __restrict__ y,
                      const float* __restrict__ params,
                      float* __restrict__ out, int N) {
  __shared__ float P[64];
  if (threadIdx.x < 62) P[threadIdx.x] = params[threadIdx.x];
  __syncthreads();
  int n = blockIdx.x * blockDim.x + threadIdx.x;
  if (n >= N) return;
  const float4* yr4 = reinterpret_cast<const float4*>(y + (size_t)n * F);
  float v[F];
  #pragma unroll
  for (int k = 0; k < 5; ++k) {
    float4 q = yr4[k];
    v[4 * k + 0] = q.x; v[4 * k + 1] = q.y;
    v[4 * k + 2] = q.z; v[4 * k + 3] = q.w;
  }
  float l0 = P[40], l1 = P[41];
  #pragma unroll
  for (int f = 0; f < F; ++f) {
    float dv = v[f] - P[42 + f];
    l0 += dv * P[f * 2 + 0];
    l1 += dv * P[f * 2 + 1];
  }
  l0 = fmaxf(l0, 0.f);
  l1 = fmaxf(l1, 0.f);
  float m = fmaxf(l0, l1);
  float e0 = __expf(l0 - m), e1 = __expf(l1 - m);
  float inv = 1.0f / (e0 + e1);
  float2 o2; o2.x = e0 * inv; o2.y = e1 * inv;
  reinterpret_cast<float2*>(out)[n] = o2;
}

extern "C" void kernel_launch(void* const* d_in, const int* in_sizes, int n_in,
                              void* d_out, int out_size, void* d_ws, size_t ws_size,
                              hipStream_t stream) {
  const float* state     = (const float*)d_in[0];
  const float* edge_attr = (const float*)d_in[1];
  const int*   eidx      = (const int*)d_in[2];
  const float* W_gcn     = (const float*)d_in[3];
  // d_in[4] = b_gcn: cancels inside batchnorm, unused.
  const float* gamma     = (const float*)d_in[5];
  const float* beta      = (const float*)d_in[6];
  const float* W_lin     = (const float*)d_in[7];
  const float* b_lin     = (const float*)d_in[8];
  float* out = (float*)d_out;

  int Ns = in_sizes[0] / F;
  int E  = in_sizes[2] / 2;
  int N  = Ns + in_sizes[1] / F;
  int H  = in_sizes[4];

  const int* src = eidx;
  const int* dst = eidx + E;

  float* ws     = (float*)d_ws;
  float* deg    = ws;
  float* dinv   = ws + N;
  float* y      = ws + 2 * (size_t)N;
  float* stats  = y + (size_t)N * F;
  float* params = stats + 256;

  hipMemsetAsync(stats, 0, 256 * sizeof(float), stream);

  const int B = 256;
  k_deg_init<<<(N + B - 1) / B, B, 0, stream>>>(deg, N);
  k_deg_acc<<<(E + B - 1) / B, B, 0, stream>>>(dst, deg, E);
  k_selfloop<<<(N * F + B - 1) / B, B, 0, stream>>>(state, edge_attr, deg, dinv, y, N, Ns);
  k_edge_scatter<<<(E * F + B - 1) / B, B, 0, stream>>>(src, dst, dinv, state, edge_attr, y, E, Ns);
  k_stats<<<(N + ROWS_CHUNK * CHUNKS - 1) / (ROWS_CHUNK * CHUNKS), B, 0, stream>>>(y, stats, N);
  k_finalize<<<1, 256, 0, stream>>>(stats, W_gcn, gamma, beta, W_lin, b_lin, params, N, H);
  k_out<<<(N + B - 1) / B, B, 0, stream>>>(y, params, out, N);
}

// Round 5
// 114.392 us; speedup vs baseline: 2.5501x; 1.3295x over previous
//
#include <hip/hip_runtime.h>

// ActorGCN collapsed-linear implementation.
// Key identity: A(xW) = (Ax)W, and BN stats of h = yW+b reduce to the
// 20x20 covariance of y. Hidden [N,1024] never materialized.
//
// Workspace layout (floats):
//   deg   : [0,   N)
//   dinv  : [N,  2N)
//   y     : [2N, 2N + 20N)
//   stats : 256 floats (20 column sums + 210 upper-tri second moments)
//   params: 64 floats  (M[40], d[2], ybar[20])
// Total = 22N + 320 floats ~= 18.4 MB.

#define F 20
#define NSTAT 230  // 20 sums + 210 upper-triangle (incl diag) products

__global__ void k_deg_init(float* __restrict__ deg, int N) {
  int n = blockIdx.x * blockDim.x + threadIdx.x;
  if (n < N) deg[n] = 1.0f;  // self-loop contributes 1
}

__global__ void k_deg_acc(const int* __restrict__ dst, float* __restrict__ deg, int E) {
  int e = blockIdx.x * blockDim.x + threadIdx.x;
  if (e < E) atomicAdd(&deg[dst[e]], 1.0f);
}

// thread per (node, feature): y[n,f] = x[n,f]/deg[n]  (self-loop term, plain store)
// also emits dinv[n] = rsqrt(deg[n]) once per node.
__global__ void k_selfloop(const float* __restrict__ state,
                           const float* __restrict__ edge_attr,
                           const float* __restrict__ deg,
                           float* __restrict__ dinv,
                           float* __restrict__ y,
                           int N, int Ns) {
  int tid = blockIdx.x * blockDim.x + threadIdx.x;
  int total = N * F;
  if (tid >= total) return;
  int n = tid / F;
  int f = tid - n * F;
  float d = deg[n];
  int sb = Ns * F;
  float x = (tid < sb) ? state[tid] : edge_attr[tid - sb];
  y[tid] = x / d;                 // dinv[n]^2 * x = x/deg
  if (f == 0) dinv[n] = rsqrtf(d);
}

// thread per (edge, feature): y[dst,f] += dinv[src]*dinv[dst]*x[src,f]
__global__ void k_edge_scatter(const int* __restrict__ src,
                               const int* __restrict__ dst,
                               const float* __restrict__ dinv,
                               const float* __restrict__ state,
                               const float* __restrict__ edge_attr,
                               float* __restrict__ y,
                               int E, int Ns) {
  int tid = blockIdx.x * blockDim.x + threadIdx.x;
  if (tid >= E * F) return;
  int e = tid / F;
  int f = tid - e * F;
  int s = src[e];
  int d = dst[e];
  float norm = dinv[s] * dinv[d];
  int xi = s * F + f;
  int sb = Ns * F;
  float x = (xi < sb) ? state[xi] : edge_attr[xi - sb];
  atomicAdd(&y[d * F + f], norm * x);
}

// Column sums + upper-tri second moments of y, LDS-staged.
// Round-5 restructure: ONE 256-row chunk per block -> 814 blocks (~3.2/CU,
// 12+ waves/CU of TLP) instead of 102 blocks @ 1 wave/SIMD (round-4 profile:
// Occupancy 4.4%, VALUBusy 3.8%, 76 us = pure unhidden LDS latency on a
// 2048-deep dependent FMA chain). Row loop unrolled x4 with independent
// accumulators to break the dependence chain. One atomicAdd per stat per
// block combines partials (230 addrs x 814 blocks, L2-pipelined).
#define SROWS 256
__global__ __launch_bounds__(256) void k_stats(const float* __restrict__ y,
                                               float* __restrict__ stats, int N) {
  __shared__ float lds[SROWS * F];  // 20 KB
  int c = threadIdx.x;
  int ci = 0, cj = 0;
  if (c >= F && c < NSTAT) {
    int k = c - F;
    int i = 0;
    while (k >= F - i) { k -= F - i; i++; }
    ci = i; cj = i + k;
  }
  long e0 = (long)blockIdx.x * (SROWS * F);
  long totalElems = (long)N * F;
  for (int i = c; i < SROWS * F; i += 256) {
    long gi = e0 + i;
    lds[i] = (gi < totalElems) ? y[gi] : 0.f;
  }
  __syncthreads();
  if (c < F) {
    float a0 = 0.f, a1 = 0.f, a2 = 0.f, a3 = 0.f;
    for (int r = 0; r < SROWS; r += 4) {
      a0 += lds[(r + 0) * F + c];
      a1 += lds[(r + 1) * F + c];
      a2 += lds[(r + 2) * F + c];
      a3 += lds[(r + 3) * F + c];
    }
    atomicAdd(&stats[c], (a0 + a1) + (a2 + a3));
  } else if (c < NSTAT) {
    float a0 = 0.f, a1 = 0.f, a2 = 0.f, a3 = 0.f;
    for (int r = 0; r < SROWS; r += 4) {
      a0 += lds[(r + 0) * F + ci] * lds[(r + 0) * F + cj];
      a1 += lds[(r + 1) * F + ci] * lds[(r + 1) * F + cj];
      a2 += lds[(r + 2) * F + ci] * lds[(r + 2) * F + cj];
      a3 += lds[(r + 3) * F + ci] * lds[(r + 3) * F + cj];
    }
    atomicAdd(&stats[c], (a0 + a1) + (a2 + a3));
  }
}

// Single block, 256 threads, launch_bounds(256,1): 4 waves -> up to 512
// VGPR/thread, so w[4][20] + m0[20] + m1[20] live comfortably in registers.
// (Rounds 2-3 at 1024 threads were capped at 64 VGPR -> scratch spill ->
// WRITE_SIZE 1.4-1.5 MB, VALUBusy 0.02%, ~110-118 us.)
// Quadform uses 210 upper-tri covariance coeffs (off-diag premultiplied by 2)
// built once in LDS; each coeff is a uniform broadcast ds_read reused for the
// thread's 4 channels. Butterfly reduce runs ONCE at the end.
__global__ __launch_bounds__(256, 1) void k_finalize(
    const float* __restrict__ stats,
    const float* __restrict__ W_gcn,
    const float* __restrict__ gamma,
    const float* __restrict__ beta,
    const float* __restrict__ W_lin,
    const float* __restrict__ b_lin,
    float* __restrict__ params,
    int N, int H) {
  __shared__ float Cu_s[210];
  __shared__ float ybar_s[F];
  __shared__ float part[4][44];
  int t = threadIdx.x;
  int lane = t & 63;
  int wv = t >> 6;
  float invN = 1.0f / (float)N;
  if (t < F) ybar_s[t] = stats[t] * invN;
  __syncthreads();
  if (t < 210) {
    int k = t;
    int i = 0;
    while (k >= F - i) { k -= F - i; i++; }
    int j = i + k;
    float cv = stats[F + t] * invN - ybar_s[i] * ybar_s[j];
    Cu_s[t] = (i == j) ? cv : 2.0f * cv;  // fold symmetry factor
  }
  __syncthreads();

  float m0[F], m1[F];
  #pragma unroll
  for (int f = 0; f < F; ++f) { m0[f] = 0.f; m1[f] = 0.f; }
  float d0 = 0.f, d1 = 0.f;

  for (int hb = 0; hb < H; hb += 4 * 256) {
    float w[4][F];
    float var[4];
    int hh[4];
    bool act[4];
    #pragma unroll
    for (int c = 0; c < 4; ++c) {
      int h = hb + c * 256 + t;
      act[c] = (h < H);
      hh[c] = act[c] ? h : 0;
      var[c] = 0.f;
      #pragma unroll
      for (int f = 0; f < F; ++f) {
        float x = W_gcn[f * H + hh[c]];  // coalesced over t
        w[c][f] = act[c] ? x : 0.f;
      }
    }
    int p = 0;
    #pragma unroll
    for (int i = 0; i < F; ++i) {
      #pragma unroll
      for (int j = i; j < F; ++j) {
        float cu = Cu_s[p];  // uniform broadcast, reused 4x
        ++p;
        #pragma unroll
        for (int c = 0; c < 4; ++c) var[c] += cu * (w[c][i] * w[c][j]);
      }
    }
    #pragma unroll
    for (int c = 0; c < 4; ++c) {
      float sg = act[c] ? (gamma[hh[c]] * rsqrtf(var[c] + 1e-5f)) : 0.f;
      float wl0 = W_lin[hh[c] * 2 + 0], wl1 = W_lin[hh[c] * 2 + 1];
      float s0 = sg * wl0, s1 = sg * wl1;
      #pragma unroll
      for (int f = 0; f < F; ++f) { m0[f] += w[c][f] * s0; m1[f] += w[c][f] * s1; }
      float bt = act[c] ? beta[hh[c]] : 0.f;
      d0 += bt * wl0;
      d1 += bt * wl1;
    }
  }

  // one butterfly reduce at the end
  #pragma unroll
  for (int f = 0; f < F; ++f) {
    float v0 = m0[f], v1 = m1[f];
    #pragma unroll
    for (int off = 32; off; off >>= 1) {
      v0 += __shfl_xor(v0, off);
      v1 += __shfl_xor(v1, off);
    }
    if (lane == 0) { part[wv][2 * f] = v0; part[wv][2 * f + 1] = v1; }
  }
  #pragma unroll
  for (int off = 32; off; off >>= 1) {
    d0 += __shfl_xor(d0, off);
    d1 += __shfl_xor(d1, off);
  }
  if (lane == 0) { part[wv][40] = d0; part[wv][41] = d1; }
  __syncthreads();

  if (t < 42) {
    float acc = 0.f;
    for (int w2 = 0; w2 < 4; ++w2) acc += part[w2][t];
    if (t >= 40) acc += b_lin[t - 40];
    params[t] = acc;
  } else if (t < 62) {
    params[t] = ybar_s[t - 42];
  }
}

// thread per node: logits = (y[n]-ybar) @ M + d; relu; 2-way softmax.
__global__ void k_out(const float* __restrict__ y,
                      const float* __restrict__ params,
                      float* __restrict__ out, int N) {
  __shared__ float P[64];
  if (threadIdx.x < 62) P[threadIdx.x] = params[threadIdx.x];
  __syncthreads();
  int n = blockIdx.x * blockDim.x + threadIdx.x;
  if (n >= N) return;
  const float4* yr4 = reinterpret_cast<const float4*>(y + (size_t)n * F);
  float v[F];
  #pragma unroll
  for (int k = 0; k < 5; ++k) {
    float4 q = yr4[k];
    v[4 * k + 0] = q.x; v[4 * k + 1] = q.y;
    v[4 * k + 2] = q.z; v[4 * k + 3] = q.w;
  }
  float l0 = P[40], l1 = P[41];
  #pragma unroll
  for (int f = 0; f < F; ++f) {
    float dv = v[f] - P[42 + f];
    l0 += dv * P[f * 2 + 0];
    l1 += dv * P[f * 2 + 1];
  }
  l0 = fmaxf(l0, 0.f);
  l1 = fmaxf(l1, 0.f);
  float m = fmaxf(l0, l1);
  float e0 = __expf(l0 - m), e1 = __expf(l1 - m);
  float inv = 1.0f / (e0 + e1);
  float2 o2; o2.x = e0 * inv; o2.y = e1 * inv;
  reinterpret_cast<float2*>(out)[n] = o2;
}

extern "C" void kernel_launch(void* const* d_in, const int* in_sizes, int n_in,
                              void* d_out, int out_size, void* d_ws, size_t ws_size,
                              hipStream_t stream) {
  const float* state     = (const float*)d_in[0];
  const float* edge_attr = (const float*)d_in[1];
  const int*   eidx      = (const int*)d_in[2];
  const float* W_gcn     = (const float*)d_in[3];
  // d_in[4] = b_gcn: cancels inside batchnorm, unused.
  const float* gamma     = (const float*)d_in[5];
  const float* beta      = (const float*)d_in[6];
  const float* W_lin     = (const float*)d_in[7];
  const float* b_lin     = (const float*)d_in[8];
  float* out = (float*)d_out;

  int Ns = in_sizes[0] / F;
  int E  = in_sizes[2] / 2;
  int N  = Ns + in_sizes[1] / F;
  int H  = in_sizes[4];

  const int* src = eidx;
  const int* dst = eidx + E;

  float* ws     = (float*)d_ws;
  float* deg    = ws;
  float* dinv   = ws + N;
  float* y      = ws + 2 * (size_t)N;
  float* stats  = y + (size_t)N * F;
  float* params = stats + 256;

  hipMemsetAsync(stats, 0, 256 * sizeof(float), stream);

  const int B = 256;
  k_deg_init<<<(N + B - 1) / B, B, 0, stream>>>(deg, N);
  k_deg_acc<<<(E + B - 1) / B, B, 0, stream>>>(dst, deg, E);
  k_selfloop<<<(N * F + B - 1) / B, B, 0, stream>>>(state, edge_attr, deg, dinv, y, N, Ns);
  k_edge_scatter<<<(E * F + B - 1) / B, B, 0, stream>>>(src, dst, dinv, state, edge_attr, y, E, Ns);
  k_stats<<<(N + SROWS - 1) / SROWS, B, 0, stream>>>(y, stats, N);
  k_finalize<<<1, 256, 0, stream>>>(stats, W_gcn, gamma, beta, W_lin, b_lin, params, N, H);
  k_out<<<(N + B - 1) / B, B, 0, stream>>>(y, params, out, N);
}